// Round 5
// baseline (2193.866 us; speedup 1.0000x reference)
//
#include <hip/hip_runtime.h>
#include <hip/hip_bf16.h>

#define B_TOT 65536

// Pure-VALU fp32 reference-mirror kernel. Round-5: 16 rows per block,
// 256 threads, 4096 blocks. Bit-identical accumulation order to baseline
// (rows are independent; per-row op order unchanged).
// Rationale: the backend register-caps to ~85 VGPR (512/6 tier) when LDS
// permits high occupancy; at 32 rows that demoted S5's 96-float acc arrays
// and killed ILP. At 16 rows the natural register footprint fits the tier:
// LDS 26 KiB -> 6 blocks/CU = 6 waves/SIMD AND full software pipelining.
// LDS timeline:
//   A_ (10KiB): xs[16][160]  ->  feat[16][128]
//   Bb (16KiB): h1[16][256]  ->  h2[16][256] -> psum[16][4][64] (swizzled)
//               -> dist[r][64] + idx[r] packed row-local in psum space
__global__ __launch_bounds__(256) void udp_kernel(
    const float* __restrict__ obs, const float* __restrict__ act,
    const float* __restrict__ obs2, const float* __restrict__ rew,
    const float* __restrict__ W0, const float* __restrict__ b0,
    const float* __restrict__ W1, const float* __restrict__ b1,
    const float* __restrict__ W2, const float* __restrict__ b2,
    const float* __restrict__ Wp, const float* __restrict__ emb,
    const float* __restrict__ sigma, float* __restrict__ out) {
  __shared__ __align__(16) float A_[2560];   // 10 KiB
  __shared__ __align__(16) float Bb[4096];   // 16 KiB
  const int t = threadIdx.x;
  const int blockRow = blockIdx.x * 16;

  float* out0 = out;                        // chosen_embedding (B,32)
  float* out1 = out + (size_t)B_TOT * 32;   // chosen_dist (B,1)
  float* out2 = out + (size_t)B_TOT * 33;   // idx (B,1) as float
  float* out3 = out + (size_t)B_TOT * 34;   // chosen_mean (B,32)
  float* out4 = out + (size_t)B_TOT * 66;   // distance (B,64)

  // ---- S1: stage x = [obs | obs2-obs | act | rew] fp32 into A_ ----
  for (int i = t; i < 16 * 160; i += 256) {
    int r = i / 160, k = i - r * 160;
    int row = blockRow + r;
    float v;
    if (k < 64)        v = obs[row * 64 + k];
    else if (k < 128)  v = obs2[row * 64 + (k - 64)] - obs[row * 64 + (k - 64)];
    else if (k < 144)  v = act[row * 16 + (k - 128)];
    else if (k == 144) v = rew[row];
    else               v = 0.f;
    A_[i] = v;
  }
  __syncthreads();

  // ---- S2: layer 0 (145 -> 256). thread = neuron t; 16 rows in regs ----
  {
    float acc[16];
#pragma unroll
    for (int r = 0; r < 16; ++r) acc[r] = 0.f;
    const float bb = b0[t];
    const float wt = W0[144 * 256 + t];  // tail weight, load early
    float w0v = W0[0 * 256 + t], w1v = W0[1 * 256 + t];
    float w2v = W0[2 * 256 + t], w3v = W0[3 * 256 + t];
    for (int k4 = 0; k4 < 144; k4 += 4) {
      const int kn = (k4 + 4 < 144) ? (k4 + 4) : 0;  // wrap: last prefetch unused
      float n0 = W0[(kn + 0) * 256 + t];
      float n1 = W0[(kn + 1) * 256 + t];
      float n2 = W0[(kn + 2) * 256 + t];
      float n3 = W0[(kn + 3) * 256 + t];
#pragma unroll
      for (int r = 0; r < 16; ++r) {
        const float4 xv = *(const float4*)&A_[r * 160 + k4];  // LDS broadcast
        acc[r] = fmaf(xv.x, w0v, acc[r]);
        acc[r] = fmaf(xv.y, w1v, acc[r]);
        acc[r] = fmaf(xv.z, w2v, acc[r]);
        acc[r] = fmaf(xv.w, w3v, acc[r]);
      }
      w0v = n0; w1v = n1; w2v = n2; w3v = n3;
    }
#pragma unroll
    for (int r = 0; r < 16; ++r) acc[r] = fmaf(A_[r * 160 + 144], wt, acc[r]);
#pragma unroll
    for (int r = 0; r < 16; ++r) {
      float v = acc[r] + bb;
      v = v > 0.f ? v : 0.01f * v;
      Bb[r * 256 + t] = v;  // h1
    }
  }
  __syncthreads();

  // ---- S3: layer 1 (256 -> 256). acc in regs; h2 overwrites h1 in Bb ----
  {
    float acc[16];
#pragma unroll
    for (int r = 0; r < 16; ++r) acc[r] = 0.f;
    const float bb = b1[t];
    float w0v = W1[0 * 256 + t], w1v = W1[1 * 256 + t];
    float w2v = W1[2 * 256 + t], w3v = W1[3 * 256 + t];
    for (int k4 = 0; k4 < 256; k4 += 4) {
      const int kn = (k4 + 4) & 255;  // wraps to 0 on last iter (unused)
      float n0 = W1[(kn + 0) * 256 + t];
      float n1 = W1[(kn + 1) * 256 + t];
      float n2 = W1[(kn + 2) * 256 + t];
      float n3 = W1[(kn + 3) * 256 + t];
#pragma unroll
      for (int r = 0; r < 16; ++r) {
        const float4 hv = *(const float4*)&Bb[r * 256 + k4];  // broadcast
        acc[r] = fmaf(hv.x, w0v, acc[r]);
        acc[r] = fmaf(hv.y, w1v, acc[r]);
        acc[r] = fmaf(hv.z, w2v, acc[r]);
        acc[r] = fmaf(hv.w, w3v, acc[r]);
      }
      w0v = n0; w1v = n1; w2v = n2; w3v = n3;
    }
    __syncthreads();  // all h1 reads done before any h2 write (same buffer)
#pragma unroll
    for (int r = 0; r < 16; ++r) {
      float v = acc[r] + bb;
      v = v > 0.f ? v : 0.01f * v;
      Bb[r * 256 + t] = v;  // h2 (overwrites h1)
    }
  }
  __syncthreads();

  // ---- S4: layer 2 (256 -> 128). thread = (neuron t&127, row-half t>>7) ----
  {
    const int n = t & 127, half = t >> 7;  // half uniform per wave
    float acc[8];
#pragma unroll
    for (int r = 0; r < 8; ++r) acc[r] = 0.f;
    const float bb = b2[n];
    float w0v = W2[0 * 128 + n], w1v = W2[1 * 128 + n];
    float w2v = W2[2 * 128 + n], w3v = W2[3 * 128 + n];
    for (int k4 = 0; k4 < 256; k4 += 4) {
      const int kn = (k4 + 4) & 255;
      float n0 = W2[(kn + 0) * 128 + n];
      float n1 = W2[(kn + 1) * 128 + n];
      float n2 = W2[(kn + 2) * 128 + n];
      float n3 = W2[(kn + 3) * 128 + n];
#pragma unroll
      for (int r = 0; r < 8; ++r) {
        const float4 hv = *(const float4*)&Bb[(half * 8 + r) * 256 + k4];
        acc[r] = fmaf(hv.x, w0v, acc[r]);
        acc[r] = fmaf(hv.y, w1v, acc[r]);
        acc[r] = fmaf(hv.z, w2v, acc[r]);
        acc[r] = fmaf(hv.w, w3v, acc[r]);
      }
      w0v = n0; w1v = n1; w2v = n2; w3v = n3;
    }
#pragma unroll
    for (int r = 0; r < 8; ++r) {
      float v = acc[r] + bb;
      v = v > 0.f ? v : 0.01f * v;
      A_[(half * 8 + r) * 128 + n] = v;  // feat in A_ (xs dead)
    }
  }
  __syncthreads();

  // ---- S5: projection + diff^2 partials (numpy pairwise tree) ----
  // thread = (env n = t&63, partial p = t>>6 wave-uniform). numpy's 8
  // accumulators r_j (j = e mod 8, m ascending); this thread owns
  // j in {2p, 2p+1}. Per m-pass compute BOTH e = 2p+8m and e+1, rows
  // processed in 2 halves of 8 (register relief); each LDS feat read
  // feeds 8 FMAs; Wp float4 loads double-buffered one f4-step ahead.
  // Per-(thread,e,row) dot keeps ascending-f4 FMA order and per-
  // accumulator m-ascending order -> bit-exact vs baseline.
  {
    const int n = t & 63, pp = t >> 6;
    float rj0[16], rj1[16];
#pragma unroll
    for (int r = 0; r < 16; ++r) { rj0[r] = 0.f; rj1[r] = 0.f; }
    const float* wb = Wp + (size_t)n * 32 * 128;
    const float* eb = emb + n * 32;
#pragma unroll 1
    for (int m = 0; m < 4; ++m) {
      const int e0 = 2 * pp + 8 * m;  // jj=0
      const int e1 = e0 + 1;          // jj=1
      const float* w0p = wb + e0 * 128;
      const float* w1p = wb + e1 * 128;
      const float em0 = eb[e0], em1 = eb[e1];
#pragma unroll 1
      for (int hh = 0; hh < 2; ++hh) {
        const int rbase = hh * 8;
        float acc0[8], acc1[8];
#pragma unroll
        for (int r = 0; r < 8; ++r) { acc0[r] = 0.f; acc1[r] = 0.f; }
        float4 wv0 = *(const float4*)(w0p);
        float4 wv1 = *(const float4*)(w1p);
        for (int f4 = 0; f4 < 128; f4 += 4) {
          const int fn = (f4 + 4) & 127;  // wrap: last prefetch harmless/in-bounds
          const float4 nv0 = *(const float4*)(w0p + fn);
          const float4 nv1 = *(const float4*)(w1p + fn);
#pragma unroll
          for (int r = 0; r < 8; ++r) {
            const float4 fv = *(const float4*)&A_[(rbase + r) * 128 + f4];  // broadcast
            acc0[r] = fmaf(fv.x, wv0.x, acc0[r]);
            acc0[r] = fmaf(fv.y, wv0.y, acc0[r]);
            acc0[r] = fmaf(fv.z, wv0.z, acc0[r]);
            acc0[r] = fmaf(fv.w, wv0.w, acc0[r]);
            acc1[r] = fmaf(fv.x, wv1.x, acc1[r]);
            acc1[r] = fmaf(fv.y, wv1.y, acc1[r]);
            acc1[r] = fmaf(fv.z, wv1.z, acc1[r]);
            acc1[r] = fmaf(fv.w, wv1.w, acc1[r]);
          }
          wv0 = nv0; wv1 = nv1;
        }
#pragma unroll
        for (int r = 0; r < 8; ++r) {
          float d0 = acc0[r] - em0;
          rj0[rbase + r] = fmaf(d0, d0, rj0[rbase + r]);  // jj=0, this m
          float d1 = acc1[r] - em1;
          rj1[rbase + r] = fmaf(d1, d1, rj1[rbase + r]);  // jj=1, this m
        }
      }
    }
    // psum into Bb (h2 dead). layout [r][pp][(n+r)&63]: write 2-way (free),
    // S6 read conflict-free.
#pragma unroll
    for (int r = 0; r < 16; ++r)
      Bb[r * 256 + pp * 64 + ((n + r) & 63)] = rj0[r] + rj1[r];
  }
  __syncthreads();

  // ---- S6: distance + argmin per row (threads 0..15) ----
  // dist[r][nr] overwrites psum[r][0][nr]: same thread reads that slot (p0)
  // earlier in the SAME iteration (nr<->n bijective), so row-local-safe.
  if (t < 16) {
    const int r = t, row = blockRow + r;
    float best = 1e30f;
    int bi = 0;
    for (int n = 0; n < 64; ++n) {
      const int nr = (n + r) & 63;  // inverse of S5 swizzle
      const float p0 = Bb[r * 256 + 0 * 64 + nr];
      const float p1 = Bb[r * 256 + 1 * 64 + nr];
      const float p2 = Bb[r * 256 + 2 * 64 + nr];
      const float p3 = Bb[r * 256 + 3 * 64 + nr];
      float s = (p0 + p1) + (p2 + p3);  // numpy pairwise combine
      float mean = s / 32.0f;           // exact (pow2)
      float sg = sigma[n];
      float den = 2.0f * sg * sg;       // np: (2.0*s)*s
      float dist = expf((-mean) / den);
      Bb[r * 256 + nr] = dist;          // swizzled dist store (conflict-free)
      if (dist < best) { best = dist; bi = n; }  // np.argmin first-min
    }
    Bb[r * 256 + 64] = (float)bi;  // idx in psum[r][1][0] space (reads done)
    out1[row] = best;
    out2[row] = (float)bi;
  }
  __syncthreads();

  // ---- S7a: distance matrix out (undo swizzle) ----
  for (int i = t; i < 16 * 64; i += 256) {
    int r = i >> 6, n = i & 63;
    out4[(size_t)(blockRow + r) * 64 + n] = Bb[r * 256 + ((n + r) & 63)];
  }
  // ---- S7b: chosen embedding (recompute f2e[idx]) + chosen mean ----
  for (int i = t; i < 16 * 32; i += 256) {
    int r = i >> 5, e = i & 31;
    int bi = (int)Bb[r * 256 + 64];
    const float* wrow = Wp + (bi * 32 + e) * 128;
    float acc = 0.f;
    for (int f4 = 0; f4 < 128; f4 += 4) {
      const float4 wv = *(const float4*)(wrow + f4);
      const float4 fv = *(const float4*)&A_[r * 128 + f4];
      acc = fmaf(fv.x, wv.x, acc);
      acc = fmaf(fv.y, wv.y, acc);
      acc = fmaf(fv.z, wv.z, acc);
      acc = fmaf(fv.w, wv.w, acc);
    }
    size_t row = (size_t)blockRow + r;
    out0[row * 32 + e] = acc;
    out3[row * 32 + e] = emb[bi * 32 + e];
  }
}

extern "C" void kernel_launch(void* const* d_in, const int* in_sizes, int n_in,
                              void* d_out, int out_size, void* d_ws, size_t ws_size,
                              hipStream_t stream) {
  const float* obs   = (const float*)d_in[0];
  const float* act   = (const float*)d_in[1];
  const float* obs2  = (const float*)d_in[2];
  const float* rew   = (const float*)d_in[3];
  const float* W0    = (const float*)d_in[4];
  const float* b0    = (const float*)d_in[5];
  const float* W1    = (const float*)d_in[6];
  const float* b1    = (const float*)d_in[7];
  const float* W2    = (const float*)d_in[8];
  const float* b2    = (const float*)d_in[9];
  const float* Wp    = (const float*)d_in[10];
  const float* e_emb = (const float*)d_in[11];
  const float* sigma = (const float*)d_in[12];

  udp_kernel<<<dim3(B_TOT / 16), dim3(256), 0, stream>>>(
      obs, act, obs2, rew, W0, b0, W1, b1, W2, b2, Wp, e_emb, sigma,
      (float*)d_out);
}

// Round 6
// 1542.588 us; speedup vs baseline: 1.4222x; 1.4222x over previous
//
#include <hip/hip_runtime.h>
#include <hip/hip_bf16.h>

#define B_TOT 65536

// Pure-VALU fp32 reference-mirror kernel. 32 rows per block, 256 threads.
// Bit-identical accumulation order to the 1552us baseline.
// Round-6: round-4 structure (52KiB LDS chaining, 3 blocks/CU) plus
// amdgpu_waves_per_eu(3,3). R3/R4 showed the allocator ignores the
// launch_bounds MINIMUM and chases 6-8 waves/EU (VGPR 84/64), demoting the
// S5 accumulator arrays and killing pipelining. max_waves=3 pins the VGPR
// budget at 512/3=170 so the ~130-float working set stays in registers
// while LDS still admits 3 blocks/CU (3*52KiB=156KiB <= 160KiB).
// Empirical: VALU-issue time is ~constant 770us across configs; wall time
// = issue/VALUBusy, so the lever is VALUBusy via ILP x residency.
// LDS timeline:
//   A_ (20KiB): xs[32][160]  ->  feat[32][128]
//   Bb (32KiB): h1[32][256]  ->  h2[32][256] -> psum[32][4][64] (swizzled)
//               -> dist[r][64] + idx[r] packed row-local in psum space
__global__ __launch_bounds__(256)
__attribute__((amdgpu_waves_per_eu(3, 3)))
void udp_kernel(
    const float* __restrict__ obs, const float* __restrict__ act,
    const float* __restrict__ obs2, const float* __restrict__ rew,
    const float* __restrict__ W0, const float* __restrict__ b0,
    const float* __restrict__ W1, const float* __restrict__ b1,
    const float* __restrict__ W2, const float* __restrict__ b2,
    const float* __restrict__ Wp, const float* __restrict__ emb,
    const float* __restrict__ sigma, float* __restrict__ out) {
  __shared__ __align__(16) float A_[5120];   // 20 KiB
  __shared__ __align__(16) float Bb[8192];   // 32 KiB
  const int t = threadIdx.x;
  const int blockRow = blockIdx.x * 32;

  float* out0 = out;                        // chosen_embedding (B,32)
  float* out1 = out + (size_t)B_TOT * 32;   // chosen_dist (B,1)
  float* out2 = out + (size_t)B_TOT * 33;   // idx (B,1) as float
  float* out3 = out + (size_t)B_TOT * 34;   // chosen_mean (B,32)
  float* out4 = out + (size_t)B_TOT * 66;   // distance (B,64)

  // ---- S1: stage x = [obs | obs2-obs | act | rew] fp32 into A_ ----
  for (int i = t; i < 32 * 160; i += 256) {
    int r = i / 160, k = i - r * 160;
    int row = blockRow + r;
    float v;
    if (k < 64)        v = obs[row * 64 + k];
    else if (k < 128)  v = obs2[row * 64 + (k - 64)] - obs[row * 64 + (k - 64)];
    else if (k < 144)  v = act[row * 16 + (k - 128)];
    else if (k == 144) v = rew[row];
    else               v = 0.f;
    A_[i] = v;
  }
  __syncthreads();

  // ---- S2: layer 0 (145 -> 256). thread = neuron t; 32 rows in regs ----
  {
    float acc[32];
#pragma unroll
    for (int r = 0; r < 32; ++r) acc[r] = 0.f;
    const float bb = b0[t];
    const float wt = W0[144 * 256 + t];  // tail weight, load early
    float w0v = W0[0 * 256 + t], w1v = W0[1 * 256 + t];
    float w2v = W0[2 * 256 + t], w3v = W0[3 * 256 + t];
    for (int k4 = 0; k4 < 144; k4 += 4) {
      const int kn = (k4 + 4 < 144) ? (k4 + 4) : 0;  // wrap: last prefetch unused
      float n0 = W0[(kn + 0) * 256 + t];
      float n1 = W0[(kn + 1) * 256 + t];
      float n2 = W0[(kn + 2) * 256 + t];
      float n3 = W0[(kn + 3) * 256 + t];
#pragma unroll
      for (int r = 0; r < 32; ++r) {
        const float4 xv = *(const float4*)&A_[r * 160 + k4];  // LDS broadcast
        acc[r] = fmaf(xv.x, w0v, acc[r]);
        acc[r] = fmaf(xv.y, w1v, acc[r]);
        acc[r] = fmaf(xv.z, w2v, acc[r]);
        acc[r] = fmaf(xv.w, w3v, acc[r]);
      }
      w0v = n0; w1v = n1; w2v = n2; w3v = n3;
    }
#pragma unroll
    for (int r = 0; r < 32; ++r) acc[r] = fmaf(A_[r * 160 + 144], wt, acc[r]);
#pragma unroll
    for (int r = 0; r < 32; ++r) {
      float v = acc[r] + bb;
      v = v > 0.f ? v : 0.01f * v;
      Bb[r * 256 + t] = v;  // h1
    }
  }
  __syncthreads();

  // ---- S3: layer 1 (256 -> 256). acc in regs; h2 overwrites h1 in Bb ----
  {
    float acc[32];
#pragma unroll
    for (int r = 0; r < 32; ++r) acc[r] = 0.f;
    const float bb = b1[t];
    float w0v = W1[0 * 256 + t], w1v = W1[1 * 256 + t];
    float w2v = W1[2 * 256 + t], w3v = W1[3 * 256 + t];
    for (int k4 = 0; k4 < 256; k4 += 4) {
      const int kn = (k4 + 4) & 255;  // wraps to 0 on last iter (unused)
      float n0 = W1[(kn + 0) * 256 + t];
      float n1 = W1[(kn + 1) * 256 + t];
      float n2 = W1[(kn + 2) * 256 + t];
      float n3 = W1[(kn + 3) * 256 + t];
#pragma unroll
      for (int r = 0; r < 32; ++r) {
        const float4 hv = *(const float4*)&Bb[r * 256 + k4];  // broadcast
        acc[r] = fmaf(hv.x, w0v, acc[r]);
        acc[r] = fmaf(hv.y, w1v, acc[r]);
        acc[r] = fmaf(hv.z, w2v, acc[r]);
        acc[r] = fmaf(hv.w, w3v, acc[r]);
      }
      w0v = n0; w1v = n1; w2v = n2; w3v = n3;
    }
    __syncthreads();  // all h1 reads done before any h2 write (same buffer)
#pragma unroll
    for (int r = 0; r < 32; ++r) {
      float v = acc[r] + bb;
      v = v > 0.f ? v : 0.01f * v;
      Bb[r * 256 + t] = v;  // h2 (overwrites h1)
    }
  }
  __syncthreads();

  // ---- S4: layer 2 (256 -> 128). thread = (neuron t&127, row-half t>>7) ----
  {
    const int n = t & 127, half = t >> 7;  // half uniform per wave
    float acc[16];
#pragma unroll
    for (int r = 0; r < 16; ++r) acc[r] = 0.f;
    const float bb = b2[n];
    float w0v = W2[0 * 128 + n], w1v = W2[1 * 128 + n];
    float w2v = W2[2 * 128 + n], w3v = W2[3 * 128 + n];
    for (int k4 = 0; k4 < 256; k4 += 4) {
      const int kn = (k4 + 4) & 255;
      float n0 = W2[(kn + 0) * 128 + n];
      float n1 = W2[(kn + 1) * 128 + n];
      float n2 = W2[(kn + 2) * 128 + n];
      float n3 = W2[(kn + 3) * 128 + n];
#pragma unroll
      for (int r = 0; r < 16; ++r) {
        const float4 hv = *(const float4*)&Bb[(half * 16 + r) * 256 + k4];
        acc[r] = fmaf(hv.x, w0v, acc[r]);
        acc[r] = fmaf(hv.y, w1v, acc[r]);
        acc[r] = fmaf(hv.z, w2v, acc[r]);
        acc[r] = fmaf(hv.w, w3v, acc[r]);
      }
      w0v = n0; w1v = n1; w2v = n2; w3v = n3;
    }
#pragma unroll
    for (int r = 0; r < 16; ++r) {
      float v = acc[r] + bb;
      v = v > 0.f ? v : 0.01f * v;
      A_[(half * 16 + r) * 128 + n] = v;  // feat in A_ (xs dead)
    }
  }
  __syncthreads();

  // ---- S5: projection + diff^2 partials (numpy pairwise tree) ----
  // thread = (env n = t&63, partial p = t>>6 wave-uniform). numpy's 8
  // accumulators r_j (j = e mod 8, m ascending); this thread owns
  // j in {2p, 2p+1}. Per m-pass compute BOTH e = 2p+8m and e+1, rows
  // processed in 2 halves of 16 (register relief); each LDS feat read
  // feeds 8 FMAs; Wp float4 loads double-buffered one f4-step ahead.
  // Per-(thread,e,row) dot keeps ascending-f4 FMA order and per-
  // accumulator m-ascending order -> bit-exact vs baseline.
  {
    const int n = t & 63, pp = t >> 6;
    float rj0[32], rj1[32];
#pragma unroll
    for (int r = 0; r < 32; ++r) { rj0[r] = 0.f; rj1[r] = 0.f; }
    const float* wb = Wp + (size_t)n * 32 * 128;
    const float* eb = emb + n * 32;
#pragma unroll 1
    for (int m = 0; m < 4; ++m) {
      const int e0 = 2 * pp + 8 * m;  // jj=0
      const int e1 = e0 + 1;          // jj=1
      const float* w0p = wb + e0 * 128;
      const float* w1p = wb + e1 * 128;
      const float em0 = eb[e0], em1 = eb[e1];
#pragma unroll 1
      for (int hh = 0; hh < 2; ++hh) {
        const int rbase = hh * 16;
        float acc0[16], acc1[16];
#pragma unroll
        for (int r = 0; r < 16; ++r) { acc0[r] = 0.f; acc1[r] = 0.f; }
        float4 wv0 = *(const float4*)(w0p);
        float4 wv1 = *(const float4*)(w1p);
        for (int f4 = 0; f4 < 128; f4 += 4) {
          const int fn = (f4 + 4) & 127;  // wrap: last prefetch harmless/in-bounds
          const float4 nv0 = *(const float4*)(w0p + fn);
          const float4 nv1 = *(const float4*)(w1p + fn);
#pragma unroll
          for (int r = 0; r < 16; ++r) {
            const float4 fv = *(const float4*)&A_[(rbase + r) * 128 + f4];  // broadcast
            acc0[r] = fmaf(fv.x, wv0.x, acc0[r]);
            acc0[r] = fmaf(fv.y, wv0.y, acc0[r]);
            acc0[r] = fmaf(fv.z, wv0.z, acc0[r]);
            acc0[r] = fmaf(fv.w, wv0.w, acc0[r]);
            acc1[r] = fmaf(fv.x, wv1.x, acc1[r]);
            acc1[r] = fmaf(fv.y, wv1.y, acc1[r]);
            acc1[r] = fmaf(fv.z, wv1.z, acc1[r]);
            acc1[r] = fmaf(fv.w, wv1.w, acc1[r]);
          }
          wv0 = nv0; wv1 = nv1;
        }
#pragma unroll
        for (int r = 0; r < 16; ++r) {
          float d0 = acc0[r] - em0;
          rj0[rbase + r] = fmaf(d0, d0, rj0[rbase + r]);  // jj=0, this m
          float d1 = acc1[r] - em1;
          rj1[rbase + r] = fmaf(d1, d1, rj1[rbase + r]);  // jj=1, this m
        }
      }
    }
    // psum into Bb (h2 dead). layout [r][pp][(n+r)&63]: write 2-way (free),
    // S6 read conflict-free.
#pragma unroll
    for (int r = 0; r < 32; ++r)
      Bb[r * 256 + pp * 64 + ((n + r) & 63)] = rj0[r] + rj1[r];
  }
  __syncthreads();

  // ---- S6: distance + argmin per row (threads 0..31) ----
  // dist[r][nr] overwrites psum[r][0][nr]: same thread reads that slot (p0)
  // earlier in the SAME iteration (nr<->n bijective), so row-local-safe.
  if (t < 32) {
    const int r = t, row = blockRow + r;
    float best = 1e30f;
    int bi = 0;
    for (int n = 0; n < 64; ++n) {
      const int nr = (n + r) & 63;  // inverse of S5 swizzle
      const float p0 = Bb[r * 256 + 0 * 64 + nr];
      const float p1 = Bb[r * 256 + 1 * 64 + nr];
      const float p2 = Bb[r * 256 + 2 * 64 + nr];
      const float p3 = Bb[r * 256 + 3 * 64 + nr];
      float s = (p0 + p1) + (p2 + p3);  // numpy pairwise combine
      float mean = s / 32.0f;           // exact (pow2)
      float sg = sigma[n];
      float den = 2.0f * sg * sg;       // np: (2.0*s)*s
      float dist = expf((-mean) / den);
      Bb[r * 256 + nr] = dist;          // swizzled dist store (conflict-free)
      if (dist < best) { best = dist; bi = n; }  // np.argmin first-min
    }
    Bb[r * 256 + 64] = (float)bi;  // idx in psum[r][1][r-slot] space (reads done)
    out1[row] = best;
    out2[row] = (float)bi;
  }
  __syncthreads();

  // ---- S7a: distance matrix out (undo swizzle) ----
  for (int i = t; i < 32 * 64; i += 256) {
    int r = i >> 6, n = i & 63;
    out4[(size_t)(blockRow + r) * 64 + n] = Bb[r * 256 + ((n + r) & 63)];
  }
  // ---- S7b: chosen embedding (recompute f2e[idx]) + chosen mean ----
  for (int i = t; i < 32 * 32; i += 256) {
    int r = i >> 5, e = i & 31;
    int bi = (int)Bb[r * 256 + 64];
    const float* wrow = Wp + (bi * 32 + e) * 128;
    float acc = 0.f;
    for (int f4 = 0; f4 < 128; f4 += 4) {
      const float4 wv = *(const float4*)(wrow + f4);
      const float4 fv = *(const float4*)&A_[r * 128 + f4];
      acc = fmaf(fv.x, wv.x, acc);
      acc = fmaf(fv.y, wv.y, acc);
      acc = fmaf(fv.z, wv.z, acc);
      acc = fmaf(fv.w, wv.w, acc);
    }
    size_t row = (size_t)blockRow + r;
    out0[row * 32 + e] = acc;
    out3[row * 32 + e] = emb[bi * 32 + e];
  }
}

extern "C" void kernel_launch(void* const* d_in, const int* in_sizes, int n_in,
                              void* d_out, int out_size, void* d_ws, size_t ws_size,
                              hipStream_t stream) {
  const float* obs   = (const float*)d_in[0];
  const float* act   = (const float*)d_in[1];
  const float* obs2  = (const float*)d_in[2];
  const float* rew   = (const float*)d_in[3];
  const float* W0    = (const float*)d_in[4];
  const float* b0    = (const float*)d_in[5];
  const float* W1    = (const float*)d_in[6];
  const float* b1    = (const float*)d_in[7];
  const float* W2    = (const float*)d_in[8];
  const float* b2    = (const float*)d_in[9];
  const float* Wp    = (const float*)d_in[10];
  const float* e_emb = (const float*)d_in[11];
  const float* sigma = (const float*)d_in[12];

  udp_kernel<<<dim3(B_TOT / 32), dim3(256), 0, stream>>>(
      obs, act, obs2, rew, W0, b0, W1, b1, W2, b2, Wp, e_emb, sigma,
      (float*)d_out);
}

// Round 8
// 1397.802 us; speedup vs baseline: 1.5695x; 1.1036x over previous
//
#include <hip/hip_runtime.h>
#include <hip/hip_bf16.h>

#define B_TOT 65536

// Pure-VALU fp32 reference-mirror kernel. 32 rows per block, 256 threads.
// Bit-identical accumulation order to the 1552us baseline.
// Round-8 (= round-7 resubmit after infra failure): R2 config (64KiB LDS,
// launch_bounds(256,2), ~128 VGPR tier -- every lower-LDS/higher-occupancy
// variant made the allocator clamp VGPRs to 84/64 and lose more ILP than
// occupancy gained).
// S2/S3/S4 register-retile to 4 neurons x 8 rows (S4: 4x4) per thread:
//  - weight loads become coalesced float4 (4x fewer load instructions)
//  - activation LDS broadcast reads drop 4x (8 per 128 FMAs, wave-uniform)
// Per-output-element accumulation order (k ascending, xyzw) unchanged.
// LDS timeline (R2 layout):
//   A_ (32KiB): xs[32][160] -> h2[32][256] -> psum[32][4][64] (swizzled)
//   Bb (32KiB): h1[32][256] -> feat[32][128] | dist@4096 (swz) | idx@6144
__global__ __launch_bounds__(256, 2) void udp_kernel(
    const float* __restrict__ obs, const float* __restrict__ act,
    const float* __restrict__ obs2, const float* __restrict__ rew,
    const float* __restrict__ W0, const float* __restrict__ b0,
    const float* __restrict__ W1, const float* __restrict__ b1,
    const float* __restrict__ W2, const float* __restrict__ b2,
    const float* __restrict__ Wp, const float* __restrict__ emb,
    const float* __restrict__ sigma, float* __restrict__ out) {
  __shared__ __align__(16) float A_[8192];
  __shared__ __align__(16) float Bb[8192];
  const int t = threadIdx.x;
  const int blockRow = blockIdx.x * 32;

  float* out0 = out;                        // chosen_embedding (B,32)
  float* out1 = out + (size_t)B_TOT * 32;   // chosen_dist (B,1)
  float* out2 = out + (size_t)B_TOT * 33;   // idx (B,1) as float
  float* out3 = out + (size_t)B_TOT * 34;   // chosen_mean (B,32)
  float* out4 = out + (size_t)B_TOT * 66;   // distance (B,64)

  // ---- S1: stage x = [obs | obs2-obs | act | rew] fp32 into A_ ----
  for (int i = t; i < 32 * 160; i += 256) {
    int r = i / 160, k = i - r * 160;
    int row = blockRow + r;
    float v;
    if (k < 64)        v = obs[row * 64 + k];
    else if (k < 128)  v = obs2[row * 64 + (k - 64)] - obs[row * 64 + (k - 64)];
    else if (k < 144)  v = act[row * 16 + (k - 128)];
    else if (k == 144) v = rew[row];
    else               v = 0.f;
    A_[i] = v;
  }
  __syncthreads();

  // ---- S2: layer 0 (145 -> 256). thread = 4 neurons x 8 rows ----
  // n4 = 4*(t&63) covers 256 neurons; rbase = 8*(t>>6) wave-uniform rows.
  {
    const int n4 = (t & 63) * 4;
    const int rbase = (t >> 6) * 8;
    float aA[8], aB[8], aC[8], aD[8];
#pragma unroll
    for (int r = 0; r < 8; ++r) { aA[r] = 0.f; aB[r] = 0.f; aC[r] = 0.f; aD[r] = 0.f; }
    const float4 bb = *(const float4*)&b0[n4];
    const float4 wt = *(const float4*)&W0[144 * 256 + n4];  // tail k=144
    float4 w0 = *(const float4*)&W0[0 * 256 + n4];
    float4 w1 = *(const float4*)&W0[1 * 256 + n4];
    float4 w2 = *(const float4*)&W0[2 * 256 + n4];
    float4 w3 = *(const float4*)&W0[3 * 256 + n4];
    for (int k4 = 0; k4 < 144; k4 += 4) {
      const int kn = (k4 + 4 < 144) ? (k4 + 4) : 0;  // wrap: last prefetch unused
      const float4 m0 = *(const float4*)&W0[(kn + 0) * 256 + n4];
      const float4 m1 = *(const float4*)&W0[(kn + 1) * 256 + n4];
      const float4 m2 = *(const float4*)&W0[(kn + 2) * 256 + n4];
      const float4 m3 = *(const float4*)&W0[(kn + 3) * 256 + n4];
#pragma unroll
      for (int r = 0; r < 8; ++r) {
        const float4 xv = *(const float4*)&A_[(rbase + r) * 160 + k4];  // broadcast
        aA[r] = fmaf(xv.x, w0.x, aA[r]); aA[r] = fmaf(xv.y, w1.x, aA[r]);
        aA[r] = fmaf(xv.z, w2.x, aA[r]); aA[r] = fmaf(xv.w, w3.x, aA[r]);
        aB[r] = fmaf(xv.x, w0.y, aB[r]); aB[r] = fmaf(xv.y, w1.y, aB[r]);
        aB[r] = fmaf(xv.z, w2.y, aB[r]); aB[r] = fmaf(xv.w, w3.y, aB[r]);
        aC[r] = fmaf(xv.x, w0.z, aC[r]); aC[r] = fmaf(xv.y, w1.z, aC[r]);
        aC[r] = fmaf(xv.z, w2.z, aC[r]); aC[r] = fmaf(xv.w, w3.z, aC[r]);
        aD[r] = fmaf(xv.x, w0.w, aD[r]); aD[r] = fmaf(xv.y, w1.w, aD[r]);
        aD[r] = fmaf(xv.z, w2.w, aD[r]); aD[r] = fmaf(xv.w, w3.w, aD[r]);
      }
      w0 = m0; w1 = m1; w2 = m2; w3 = m3;
    }
#pragma unroll
    for (int r = 0; r < 8; ++r) {
      const float xt = A_[(rbase + r) * 160 + 144];
      aA[r] = fmaf(xt, wt.x, aA[r]);
      aB[r] = fmaf(xt, wt.y, aB[r]);
      aC[r] = fmaf(xt, wt.z, aC[r]);
      aD[r] = fmaf(xt, wt.w, aD[r]);
    }
#pragma unroll
    for (int r = 0; r < 8; ++r) {
      float4 v;
      v.x = aA[r] + bb.x; v.x = v.x > 0.f ? v.x : 0.01f * v.x;
      v.y = aB[r] + bb.y; v.y = v.y > 0.f ? v.y : 0.01f * v.y;
      v.z = aC[r] + bb.z; v.z = v.z > 0.f ? v.z : 0.01f * v.z;
      v.w = aD[r] + bb.w; v.w = v.w > 0.f ? v.w : 0.01f * v.w;
      *(float4*)&Bb[(rbase + r) * 256 + n4] = v;  // h1 (conflict-free b128)
    }
  }
  __syncthreads();

  // ---- S3: layer 1 (256 -> 256). 4 neurons x 8 rows; h2 -> A_ (xs dead) ----
  {
    const int n4 = (t & 63) * 4;
    const int rbase = (t >> 6) * 8;
    float aA[8], aB[8], aC[8], aD[8];
#pragma unroll
    for (int r = 0; r < 8; ++r) { aA[r] = 0.f; aB[r] = 0.f; aC[r] = 0.f; aD[r] = 0.f; }
    const float4 bb = *(const float4*)&b1[n4];
    float4 w0 = *(const float4*)&W1[0 * 256 + n4];
    float4 w1 = *(const float4*)&W1[1 * 256 + n4];
    float4 w2 = *(const float4*)&W1[2 * 256 + n4];
    float4 w3 = *(const float4*)&W1[3 * 256 + n4];
    for (int k4 = 0; k4 < 256; k4 += 4) {
      const int kn = (k4 + 4) & 255;  // wraps to 0 on last iter (unused)
      const float4 m0 = *(const float4*)&W1[(kn + 0) * 256 + n4];
      const float4 m1 = *(const float4*)&W1[(kn + 1) * 256 + n4];
      const float4 m2 = *(const float4*)&W1[(kn + 2) * 256 + n4];
      const float4 m3 = *(const float4*)&W1[(kn + 3) * 256 + n4];
#pragma unroll
      for (int r = 0; r < 8; ++r) {
        const float4 xv = *(const float4*)&Bb[(rbase + r) * 256 + k4];  // broadcast
        aA[r] = fmaf(xv.x, w0.x, aA[r]); aA[r] = fmaf(xv.y, w1.x, aA[r]);
        aA[r] = fmaf(xv.z, w2.x, aA[r]); aA[r] = fmaf(xv.w, w3.x, aA[r]);
        aB[r] = fmaf(xv.x, w0.y, aB[r]); aB[r] = fmaf(xv.y, w1.y, aB[r]);
        aB[r] = fmaf(xv.z, w2.y, aB[r]); aB[r] = fmaf(xv.w, w3.y, aB[r]);
        aC[r] = fmaf(xv.x, w0.z, aC[r]); aC[r] = fmaf(xv.y, w1.z, aC[r]);
        aC[r] = fmaf(xv.z, w2.z, aC[r]); aC[r] = fmaf(xv.w, w3.z, aC[r]);
        aD[r] = fmaf(xv.x, w0.w, aD[r]); aD[r] = fmaf(xv.y, w1.w, aD[r]);
        aD[r] = fmaf(xv.z, w2.w, aD[r]); aD[r] = fmaf(xv.w, w3.w, aD[r]);
      }
      w0 = m0; w1 = m1; w2 = m2; w3 = m3;
    }
#pragma unroll
    for (int r = 0; r < 8; ++r) {
      float4 v;
      v.x = aA[r] + bb.x; v.x = v.x > 0.f ? v.x : 0.01f * v.x;
      v.y = aB[r] + bb.y; v.y = v.y > 0.f ? v.y : 0.01f * v.y;
      v.z = aC[r] + bb.z; v.z = v.z > 0.f ? v.z : 0.01f * v.z;
      v.w = aD[r] + bb.w; v.w = v.w > 0.f ? v.w : 0.01f * v.w;
      *(float4*)&A_[(rbase + r) * 256 + n4] = v;  // h2 (xs dead post-S2 barrier)
    }
  }
  __syncthreads();

  // ---- S4: layer 2 (256 -> 128). thread = 4 neurons x 4 rows ----
  // n4 = 4*(t&31); rbase = 4*(t>>5) (2 distinct per wave -> free 2-way).
  {
    const int n4 = (t & 31) * 4;
    const int rbase = (t >> 5) * 4;
    float aA[4], aB[4], aC[4], aD[4];
#pragma unroll
    for (int r = 0; r < 4; ++r) { aA[r] = 0.f; aB[r] = 0.f; aC[r] = 0.f; aD[r] = 0.f; }
    const float4 bb = *(const float4*)&b2[n4];
    float4 w0 = *(const float4*)&W2[0 * 128 + n4];
    float4 w1 = *(const float4*)&W2[1 * 128 + n4];
    float4 w2 = *(const float4*)&W2[2 * 128 + n4];
    float4 w3 = *(const float4*)&W2[3 * 128 + n4];
    for (int k4 = 0; k4 < 256; k4 += 4) {
      const int kn = (k4 + 4) & 255;
      const float4 m0 = *(const float4*)&W2[(kn + 0) * 128 + n4];
      const float4 m1 = *(const float4*)&W2[(kn + 1) * 128 + n4];
      const float4 m2 = *(const float4*)&W2[(kn + 2) * 128 + n4];
      const float4 m3 = *(const float4*)&W2[(kn + 3) * 128 + n4];
#pragma unroll
      for (int r = 0; r < 4; ++r) {
        const float4 xv = *(const float4*)&A_[(rbase + r) * 256 + k4];
        aA[r] = fmaf(xv.x, w0.x, aA[r]); aA[r] = fmaf(xv.y, w1.x, aA[r]);
        aA[r] = fmaf(xv.z, w2.x, aA[r]); aA[r] = fmaf(xv.w, w3.x, aA[r]);
        aB[r] = fmaf(xv.x, w0.y, aB[r]); aB[r] = fmaf(xv.y, w1.y, aB[r]);
        aB[r] = fmaf(xv.z, w2.y, aB[r]); aB[r] = fmaf(xv.w, w3.y, aB[r]);
        aC[r] = fmaf(xv.x, w0.z, aC[r]); aC[r] = fmaf(xv.y, w1.z, aC[r]);
        aC[r] = fmaf(xv.z, w2.z, aC[r]); aC[r] = fmaf(xv.w, w3.z, aC[r]);
        aD[r] = fmaf(xv.x, w0.w, aD[r]); aD[r] = fmaf(xv.y, w1.w, aD[r]);
        aD[r] = fmaf(xv.z, w2.w, aD[r]); aD[r] = fmaf(xv.w, w3.w, aD[r]);
      }
      w0 = m0; w1 = m1; w2 = m2; w3 = m3;
    }
#pragma unroll
    for (int r = 0; r < 4; ++r) {
      float4 v;
      v.x = aA[r] + bb.x; v.x = v.x > 0.f ? v.x : 0.01f * v.x;
      v.y = aB[r] + bb.y; v.y = v.y > 0.f ? v.y : 0.01f * v.y;
      v.z = aC[r] + bb.z; v.z = v.z > 0.f ? v.z : 0.01f * v.z;
      v.w = aD[r] + bb.w; v.w = v.w > 0.f ? v.w : 0.01f * v.w;
      *(float4*)&Bb[(rbase + r) * 128 + n4] = v;  // feat in Bb[0..4095]
    }
  }
  __syncthreads();

  // ---- S5: projection + diff^2 partials (numpy pairwise tree) ----
  // thread = (env n = t&63, partial p = t>>6 wave-uniform). numpy's 8
  // accumulators r_j (j = e mod 8, m ascending); this thread owns
  // j in {2p, 2p+1}. Per m-pass compute BOTH e = 2p+8m and e+1, rows
  // processed in 2 halves of 16; each LDS feat read feeds 8 FMAs;
  // Wp float4 loads double-buffered one f4-step ahead. Bit-exact.
  {
    const int n = t & 63, pp = t >> 6;
    float rj0[32], rj1[32];
#pragma unroll
    for (int r = 0; r < 32; ++r) { rj0[r] = 0.f; rj1[r] = 0.f; }
    const float* wb = Wp + (size_t)n * 32 * 128;
    const float* eb = emb + n * 32;
#pragma unroll 1
    for (int m = 0; m < 4; ++m) {
      const int e0 = 2 * pp + 8 * m;  // jj=0
      const int e1 = e0 + 1;          // jj=1
      const float* w0p = wb + e0 * 128;
      const float* w1p = wb + e1 * 128;
      const float em0 = eb[e0], em1 = eb[e1];
#pragma unroll 1
      for (int hh = 0; hh < 2; ++hh) {
        const int rbase = hh * 16;
        float acc0[16], acc1[16];
#pragma unroll
        for (int r = 0; r < 16; ++r) { acc0[r] = 0.f; acc1[r] = 0.f; }
        float4 wv0 = *(const float4*)(w0p);
        float4 wv1 = *(const float4*)(w1p);
        for (int f4 = 0; f4 < 128; f4 += 4) {
          const int fn = (f4 + 4) & 127;  // wrap: last prefetch harmless/in-bounds
          const float4 nv0 = *(const float4*)(w0p + fn);
          const float4 nv1 = *(const float4*)(w1p + fn);
#pragma unroll
          for (int r = 0; r < 16; ++r) {
            const float4 fv = *(const float4*)&Bb[(rbase + r) * 128 + f4];  // broadcast
            acc0[r] = fmaf(fv.x, wv0.x, acc0[r]);
            acc0[r] = fmaf(fv.y, wv0.y, acc0[r]);
            acc0[r] = fmaf(fv.z, wv0.z, acc0[r]);
            acc0[r] = fmaf(fv.w, wv0.w, acc0[r]);
            acc1[r] = fmaf(fv.x, wv1.x, acc1[r]);
            acc1[r] = fmaf(fv.y, wv1.y, acc1[r]);
            acc1[r] = fmaf(fv.z, wv1.z, acc1[r]);
            acc1[r] = fmaf(fv.w, wv1.w, acc1[r]);
          }
          wv0 = nv0; wv1 = nv1;
        }
#pragma unroll
        for (int r = 0; r < 16; ++r) {
          float d0 = acc0[r] - em0;
          rj0[rbase + r] = fmaf(d0, d0, rj0[rbase + r]);  // jj=0, this m
          float d1 = acc1[r] - em1;
          rj1[rbase + r] = fmaf(d1, d1, rj1[rbase + r]);  // jj=1, this m
        }
      }
    }
    // psum into A_ (h2 dead). layout [r][pp][(n+r)&63]: write 2-way (free),
    // S6 read conflict-free.
#pragma unroll
    for (int r = 0; r < 32; ++r)
      A_[r * 256 + pp * 64 + ((n + r) & 63)] = rj0[r] + rj1[r];
  }
  __syncthreads();

  // ---- S6: distance + argmin per row (threads 0..31) ----
  if (t < 32) {
    const int r = t, row = blockRow + r;
    float best = 1e30f;
    int bi = 0;
    for (int n = 0; n < 64; ++n) {
      const int nr = (n + r) & 63;  // inverse of S5 swizzle
      const float p0 = A_[r * 256 + 0 * 64 + nr];
      const float p1 = A_[r * 256 + 1 * 64 + nr];
      const float p2 = A_[r * 256 + 2 * 64 + nr];
      const float p3 = A_[r * 256 + 3 * 64 + nr];
      float s = (p0 + p1) + (p2 + p3);  // numpy pairwise combine
      float mean = s / 32.0f;           // exact (pow2)
      float sg = sigma[n];
      float den = 2.0f * sg * sg;       // np: (2.0*s)*s
      float dist = expf((-mean) / den);
      Bb[4096 + r * 64 + nr] = dist;    // swizzled dist store (conflict-free)
      if (dist < best) { best = dist; bi = n; }  // np.argmin first-min
    }
    Bb[6144 + r] = (float)bi;
    out1[row] = best;
    out2[row] = (float)bi;
  }
  __syncthreads();

  // ---- S7a: distance matrix out (undo swizzle) ----
  for (int i = t; i < 32 * 64; i += 256) {
    int r = i >> 6, n = i & 63;
    out4[(size_t)(blockRow + r) * 64 + n] = Bb[4096 + r * 64 + ((n + r) & 63)];
  }
  // ---- S7b: chosen embedding (recompute f2e[idx]) + chosen mean ----
  for (int i = t; i < 32 * 32; i += 256) {
    int r = i >> 5, e = i & 31;
    int bi = (int)Bb[6144 + r];
    const float* wrow = Wp + (bi * 32 + e) * 128;
    float acc = 0.f;
    for (int f4 = 0; f4 < 128; f4 += 4) {
      const float4 wv = *(const float4*)(wrow + f4);
      const float4 fv = *(const float4*)&Bb[r * 128 + f4];
      acc = fmaf(fv.x, wv.x, acc);
      acc = fmaf(fv.y, wv.y, acc);
      acc = fmaf(fv.z, wv.z, acc);
      acc = fmaf(fv.w, wv.w, acc);
    }
    size_t row = (size_t)blockRow + r;
    out0[row * 32 + e] = acc;
    out3[row * 32 + e] = emb[bi * 32 + e];
  }
}

extern "C" void kernel_launch(void* const* d_in, const int* in_sizes, int n_in,
                              void* d_out, int out_size, void* d_ws, size_t ws_size,
                              hipStream_t stream) {
  const float* obs   = (const float*)d_in[0];
  const float* act   = (const float*)d_in[1];
  const float* obs2  = (const float*)d_in[2];
  const float* rew   = (const float*)d_in[3];
  const float* W0    = (const float*)d_in[4];
  const float* b0    = (const float*)d_in[5];
  const float* W1    = (const float*)d_in[6];
  const float* b1    = (const float*)d_in[7];
  const float* W2    = (const float*)d_in[8];
  const float* b2    = (const float*)d_in[9];
  const float* Wp    = (const float*)d_in[10];
  const float* e_emb = (const float*)d_in[11];
  const float* sigma = (const float*)d_in[12];

  udp_kernel<<<dim3(B_TOT / 32), dim3(256), 0, stream>>>(
      obs, act, obs2, rew, W0, b0, W1, b1, W2, b2, Wp, e_emb, sigma,
      (float*)d_out);
}